// Round 4
// baseline (534.224 us; speedup 1.0000x reference)
//
#include <hip/hip_runtime.h>
#include <stdint.h>

// CTC forward NLL, B=32, T=2000, V=1024, S=128, L=2S+1=257.
// Phase 1 (full GPU): stage one 4 KB log-prob row in LDS (coalesced float4),
//   gather the 129 needed entries, exp, store labels[B][T][128] fp32 (512 B
//   aligned rows) + pbuf[B][T] blank probs in d_ws.
// Phase 2 (32 blocks x 1 wave): linear-domain DP, per-lane block-floating-
//   point exponents, DPP wave_shr:1 neighbor exchange. Emissions are DMA'd
//   global->LDS via global_load_lds into a 16-slot ring (3072 B/chunk = 6
//   steps), prefetch distance 12 chunks, paced with s_waitcnt vmcnt(33)
//   (never 0). LDS->reg via 2-chunk ping-pong. pb row (8 KB) staged wholly
//   in LDS at start.

#define LOG2E_F 1.4426950408889634f
#define LN2_F   0.6931471805599453f

constexpr int CB = 32;       // batch
constexpr int CT = 2000;     // time
constexpr int CV = 1024;     // vocab
constexpr int CS = 128;      // max target len
constexpr int RF = 128;      // floats per label row (512 B)
constexpr float PMIN = 9.5367431640625e-07f;  // 2^-20: 6-step window >= 2^-120, no flush

constexpr int NSLOT = 16;    // LDS ring slots (power of 2)
constexpr int DPF   = 12;    // prefetch distance in chunks (72 steps ahead)
constexpr int SLOTF = 6 * RF;  // 768 floats = 3072 B per chunk

// ---------------- phase 1: coalesced row load -> LDS gather -> exp ----------------
__global__ __launch_bounds__(256) void ctc_gather(const float* __restrict__ lp,
                                                  const int* __restrict__ targets,
                                                  float* __restrict__ labels,
                                                  float* __restrict__ pbuf,
                                                  float* __restrict__ out) {
    __shared__ float row[CV];
    const int bt  = blockIdx.x;      // b*CT + t
    const int tid = threadIdx.x;     // 0..255
    const int b   = bt / CT;
    ((float4*)row)[tid] = ((const float4*)(lp + (size_t)bt * CV))[tid];
    __syncthreads();
    if (tid < CS) {
        const int tg = targets[b * CS + tid];
        labels[(size_t)bt * RF + tid] = fmaxf(exp2f(row[tg] * LOG2E_F), PMIN);
        if (tid == 0) {
            pbuf[bt] = fmaxf(exp2f(row[0] * LOG2E_F), PMIN);
            if (bt == 0) out[0] = 0.f;   // zero the atomic accumulator
        }
    }
}

// ---------------- DPP helpers ----------------
__device__ __forceinline__ float dpp_wshr1(float x) {   // lane n <- lane n-1, lane0 <- 0
    return __int_as_float(__builtin_amdgcn_update_dpp(
        0, __float_as_int(x), 0x138, 0xF, 0xF, true));
}
__device__ __forceinline__ int dpp_wshr1_i(int x) {
    return __builtin_amdgcn_update_dpp(0, x, 0x138, 0xF, 0xF, true);
}

// ---------------- async global->LDS DMA (16 B/lane, wave-uniform LDS base) ----
typedef __attribute__((address_space(1))) uint32_t gu32;
typedef __attribute__((address_space(3))) uint32_t lu32;
__device__ __forceinline__ void dma16(const float* g, float* l) {
    __builtin_amdgcn_global_load_lds((const gu32*)g, (lu32*)l, 16, 0, 0);
}

// ---------------- phase 2: the DP ----------------
struct Chunk { float2 lab[6]; float pb[6]; };

__device__ __forceinline__ void ld_regs(Chunk& ch, const float* slot,
                                        const float* pbp, int lane) {
#pragma unroll
    for (int u = 0; u < 6; ++u) {
        ch.lab[u] = *(const float2*)(slot + u * RF + 2 * lane);  // ds_read_b64
        ch.pb[u]  = pbp[u];                                      // LDS broadcast
    }
}

__device__ __forceinline__ void run6(const Chunk& ch, float& a0, float& a1,
                                     float& a2, float& a3, float& aX,
                                     float msk1, float msk3, float f) {
#pragma unroll
    for (int u = 0; u < 6; ++u) {
        const float pb = ch.pb[u];
        const float u3 = dpp_wshr1(a3) * f;              // old alpha[4i-1], rescaled
        const float n0 = (a0 + u3) * pb;                 // blank 4i
        const float n1 = fmaf(msk1, u3, a1 + a0) * ch.lab[u].x;  // label s=2i
        const float n2 = (a2 + a1) * pb;                 // blank 4i+2
        const float n3 = fmaf(msk3, a1, a3 + a2) * ch.lab[u].y;  // label s=2i+1
        const float nX = (aX + a3) * pb;                 // cell 256 (lane 63 only valid)
        a0 = n0; a1 = n1; a2 = n2; a3 = n3; aX = nX;
    }
}

// Per-lane renorm; virgin lanes adopt left neighbor's exponent (4 DPP hops);
// f = 2^(Sc_left - Sc_self) for next window's neighbor rescale.
__device__ __forceinline__ void renorm(float& a0, float& a1, float& a2,
                                       float& a3, float& aX, int& Sc, float& f) {
    const float m = fmaxf(fmaxf(fmaxf(a0, a1), fmaxf(a2, a3)), aX);
    const bool active = (m > 0.f);
    const int E = active ? (((__float_as_int(m) >> 23) & 0xFF) - 126) : 0;
    const float s = __int_as_float((127 - E) << 23);   // exact 2^-E
    a0 *= s; a1 *= s; a2 *= s; a3 *= s; aX *= s;
    Sc += E;
#pragma unroll
    for (int k = 0; k < 4; ++k) {
        const int scl = dpp_wshr1_i(Sc);
        Sc = active ? Sc : scl;
    }
    int d = dpp_wshr1_i(Sc) - Sc;
    d = min(126, max(-126, d));
    f = __int_as_float((d + 127) << 23);               // exact 2^d
}

__device__ __forceinline__ void prefetch_chunk(const float* lab_base, float* ring,
                                               int cc, int slot, int lane) {
    const float* src = lab_base + (size_t)(1 + 6 * cc) * RF + lane * 4;
    float* dst = ring + slot * SLOTF;
    dma16(src,       dst);
    dma16(src + 256, dst + 256);
    dma16(src + 512, dst + 512);
}

__global__ __launch_bounds__(64) void ctc_dp(
        const float* __restrict__ labels, const float* __restrict__ pbuf,
        const int* __restrict__ targets, const int* __restrict__ in_len,
        const int* __restrict__ tg_len, float* __restrict__ out) {
    __shared__ float ring[NSLOT * SLOTF];   // 48 KB
    __shared__ float pb_lds[CT];            // 8 KB
    const int b = blockIdx.x;
    const int lane = threadIdx.x;            // 0..63, owns cells 4i..4i+3
    const int Tb = in_len[b];
    const int Sb = tg_len[b];
    const float* lab_base = labels + (size_t)b * CT * RF;
    const float* pb_base  = pbuf + (size_t)b * CT;

    const int tg0 = targets[b * CS + 2 * lane];
    const int tg1 = targets[b * CS + 2 * lane + 1];
    const int tgm = dpp_wshr1_i(tg1);        // targets[2i-1] (lane0: 0)
    const float msk1 = (tg0 != tgm) ? 1.f : 0.f;
    const float msk3 = (tg1 != tg0) ? 1.f : 0.f;

    // t=0 init (plain global loads, issued & consumed before any DMA)
    float a0 = 0.f, a1 = 0.f, a2 = 0.f, a3 = 0.f, aX = 0.f;
    {
        const float pb0 = pb_base[0];
        const float pl0 = lab_base[0];
        if (lane == 0) { a0 = pb0; a1 = pl0; }
    }
    int Sc = 0;
    float f = 1.f;
    renorm(a0, a1, a2, a3, aX, Sc, f);

    const int NC = (Tb - 1) / 6;             // full 6-step chunks from t=1

    // stage entire pb row into LDS: 8 x 1024 B (last one overlapped to stay in-bounds)
#pragma unroll
    for (int k = 0; k < 8; ++k) {
        int off = k * 1024;                      // bytes
        if (off + 1024 > CT * 4) off = CT * 4 - 1024;
        dma16(pb_base + off / 4 + lane * 4, pb_lds + off / 4);
    }
    // prologue: prefetch chunks 0..DPF-1 (clamped; duplicate content harmless)
    if (NC >= 1) {
#pragma unroll
        for (int k = 0; k < DPF; ++k)
            prefetch_chunk(lab_base, ring, min(k, NC - 1), k & (NSLOT - 1), lane);

        // vmcnt accounting: 8 pb loads + 3 per chunk. Waiting vmcnt(33) after
        // issuing chunk c+DPF's 3 loads guarantees chunks <= c+1 are in LDS.
        asm volatile("s_waitcnt vmcnt(33)" ::: "memory");
        Chunk cur, nxt;
        ld_regs(cur, ring + 0, pb_lds + 1, lane);
        int c = 0;
        while (true) {
            prefetch_chunk(lab_base, ring, min(c + DPF, NC - 1),
                           (c + DPF) & (NSLOT - 1), lane);
            asm volatile("s_waitcnt vmcnt(33)" ::: "memory");
            if (c + 1 < NC)
                ld_regs(nxt, ring + ((c + 1) & (NSLOT - 1)) * SLOTF,
                        pb_lds + 1 + 6 * (c + 1), lane);
            run6(cur, a0, a1, a2, a3, aX, msk1, msk3, f);
            renorm(a0, a1, a2, a3, aX, Sc, f);
            if (++c >= NC) break;

            prefetch_chunk(lab_base, ring, min(c + DPF, NC - 1),
                           (c + DPF) & (NSLOT - 1), lane);
            asm volatile("s_waitcnt vmcnt(33)" ::: "memory");
            if (c + 1 < NC)
                ld_regs(cur, ring + ((c + 1) & (NSLOT - 1)) * SLOTF,
                        pb_lds + 1 + 6 * (c + 1), lane);
            run6(nxt, a0, a1, a2, a3, aX, msk1, msk3, f);
            renorm(a0, a1, a2, a3, aX, Sc, f);
            if (++c >= NC) break;
        }
    }
    // tail: t = 1+6*NC .. Tb-1 (<=5 steps)
    for (int t = 1 + 6 * NC; t < Tb; ++t) {
        const float2 lb = *(const float2*)(lab_base + (size_t)t * RF + 2 * lane);
        const float pb = pb_lds[t];
        const float u3 = dpp_wshr1(a3) * f;
        const float n0 = (a0 + u3) * pb;
        const float n1 = fmaf(msk1, u3, a1 + a0) * lb.x;
        const float n2 = (a2 + a1) * pb;
        const float n3 = fmaf(msk3, a1, a3 + a2) * lb.y;
        const float nX = (aX + a3) * pb;
        a0 = n0; a1 = n1; a2 = n2; a3 = n3; aX = nX;
    }

    // final: ll = log(alpha[2*Sb] + alpha[2*Sb-1]); per-lane scales -> LSE
    const int idx1 = 2 * Sb;
    const int idx2 = (idx1 - 1 > 0) ? (idx1 - 1) : 0;
    const int b4 = 4 * lane;
    float cres = 0.f;
    if (b4 + 0 == idx1 || b4 + 0 == idx2) cres += a0;
    if (b4 + 1 == idx1 || b4 + 1 == idx2) cres += a1;
    if (b4 + 2 == idx1 || b4 + 2 == idx2) cres += a2;
    if (b4 + 3 == idx1 || b4 + 3 == idx2) cres += a3;
    if (lane == 63 && (idx1 == 256 || idx2 == 256)) cres += aX;

    float l2 = (cres > 0.f) ? (log2f(cres) + (float)Sc) : -1e30f;
    float M = l2;
#pragma unroll
    for (int m = 1; m < 64; m <<= 1) M = fmaxf(M, __shfl_xor(M, m, 64));
    float e = (cres > 0.f) ? exp2f(l2 - M) : 0.f;
#pragma unroll
    for (int m = 1; m < 64; m <<= 1) e += __shfl_xor(e, m, 64);
    if (lane == 0) {
        const float ll = (M + log2f(e)) * LN2_F;
        atomicAdd(out, -ll);
    }
}

extern "C" void kernel_launch(void* const* d_in, const int* in_sizes, int n_in,
                              void* d_out, int out_size, void* d_ws, size_t ws_size,
                              hipStream_t stream) {
    (void)in_sizes; (void)n_in; (void)out_size; (void)ws_size;
    const float* lp      = (const float*)d_in[0];
    const int*   targets = (const int*)d_in[1];
    const int*   in_len  = (const int*)d_in[2];
    const int*   tg_len  = (const int*)d_in[3];
    float* out    = (float*)d_out;
    float* labels = (float*)d_ws;                               // 32.77 MB
    float* pbuf   = (float*)d_ws + (size_t)CB * CT * RF;        // +256 KB

    ctc_gather<<<dim3(CB * CT), dim3(256), 0, stream>>>(lp, targets, labels, pbuf, out);
    ctc_dp<<<dim3(CB), dim3(64), 0, stream>>>(labels, pbuf, targets, in_len, tg_len, out);
}

// Round 5
// 428.498 us; speedup vs baseline: 1.2467x; 1.2467x over previous
//
#include <hip/hip_runtime.h>
#include <stdint.h>

// CTC forward NLL, B=32, T=2000, V=1024, S=128, L=2S+1=257.
// Phase 1 (full GPU): stage one 4 KB log-prob row in LDS (coalesced float4),
//   gather the 129 needed entries, exp, store labels[B][T][128] fp32 (512 B
//   rows) + pbuf[B][T] blank probs in d_ws.
// Phase 2 (32 blocks x 1 wave): linear-domain DP, per-lane block-floating-
//   point exponents, DPP wave_shr:1 neighbor exchange. Emission labels are
//   prefetched via an 8-slot REGISTER ring (8 B/lane/row coalesced
//   global_load_dwordx2 in asm volatile, 96 VGPRs), paced by asm
//   s_waitcnt vmcnt(42) with the consumed slot's registers tied as "+v"
//   operands. All loads+waits are volatile asm -> the compiler cannot
//   collapse the ring (r3 failure) or insert its own drains (r4 failure).
//   pb row staged once to LDS (8 KB) before the loop.

#define LOG2E_F 1.4426950408889634f
#define LN2_F   0.6931471805599453f

constexpr int CB = 32;       // batch
constexpr int CT = 2000;     // time
constexpr int CV = 1024;     // vocab
constexpr int CS = 128;      // max target len
constexpr int RF = 128;      // floats per label row (512 B)
constexpr float PMIN = 9.5367431640625e-07f;  // 2^-20: 6-step window >= 2^-120, no flush

// ---------------- phase 1: coalesced row load -> LDS gather -> exp ----------------
__global__ __launch_bounds__(256) void ctc_gather(const float* __restrict__ lp,
                                                  const int* __restrict__ targets,
                                                  float* __restrict__ labels,
                                                  float* __restrict__ pbuf,
                                                  float* __restrict__ out) {
    __shared__ float row[CV];
    const int bt  = blockIdx.x;      // b*CT + t
    const int tid = threadIdx.x;     // 0..255
    const int b   = bt / CT;
    ((float4*)row)[tid] = ((const float4*)(lp + (size_t)bt * CV))[tid];
    __syncthreads();
    if (tid < CS) {
        const int tg = targets[b * CS + tid];
        labels[(size_t)bt * RF + tid] = fmaxf(exp2f(row[tg] * LOG2E_F), PMIN);
        if (tid == 0) {
            pbuf[bt] = fmaxf(exp2f(row[0] * LOG2E_F), PMIN);
            if (bt == 0) out[0] = 0.f;   // zero the atomic accumulator
        }
    }
}

// ---------------- DPP helpers ----------------
__device__ __forceinline__ float dpp_wshr1(float x) {   // lane n <- lane n-1, lane0 <- 0
    return __int_as_float(__builtin_amdgcn_update_dpp(
        0, __float_as_int(x), 0x138, 0xF, 0xF, true));
}
__device__ __forceinline__ int dpp_wshr1_i(int x) {
    return __builtin_amdgcn_update_dpp(0, x, 0x138, 0xF, 0xF, true);
}

// ---------------- phase 2: the DP ----------------
__device__ __forceinline__ void run6(const float2 (&lab)[6], const float (&pv)[6],
                                     float& a0, float& a1, float& a2, float& a3,
                                     float& aX, float msk1, float msk3, float f) {
#pragma unroll
    for (int u = 0; u < 6; ++u) {
        const float pb = pv[u];
        const float u3 = dpp_wshr1(a3) * f;              // old alpha[4i-1], rescaled
        const float n0 = (a0 + u3) * pb;                 // blank 4i
        const float n1 = fmaf(msk1, u3, a1 + a0) * lab[u].x;  // label s=2i
        const float n2 = (a2 + a1) * pb;                 // blank 4i+2
        const float n3 = fmaf(msk3, a1, a3 + a2) * lab[u].y;  // label s=2i+1
        const float nX = (aX + a3) * pb;                 // cell 256 (lane 63 only valid)
        a0 = n0; a1 = n1; a2 = n2; a3 = n3; aX = nX;
    }
}

// Per-lane renorm; virgin lanes adopt left neighbor's exponent (4 DPP hops);
// f = 2^(Sc_left - Sc_self) for next window's neighbor rescale.
__device__ __forceinline__ void renorm(float& a0, float& a1, float& a2,
                                       float& a3, float& aX, int& Sc, float& f) {
    const float m = fmaxf(fmaxf(fmaxf(a0, a1), fmaxf(a2, a3)), aX);
    const bool active = (m > 0.f);
    const int E = active ? (((__float_as_int(m) >> 23) & 0xFF) - 126) : 0;
    const float s = __int_as_float((127 - E) << 23);   // exact 2^-E
    a0 *= s; a1 *= s; a2 *= s; a3 *= s; aX *= s;
    Sc += E;
#pragma unroll
    for (int k = 0; k < 4; ++k) {
        const int scl = dpp_wshr1_i(Sc);
        Sc = active ? Sc : scl;
    }
    int d = dpp_wshr1_i(Sc) - Sc;
    d = min(126, max(-126, d));
    f = __int_as_float((d + 127) << 23);               // exact 2^d
}

// issue 6 coalesced 8B-per-lane loads for chunk cc into ring slot SLOT
#define PF6(SLOT, cc) do {                                                          \
    const float* _s = lab_base + (size_t)(1 + 6 * (size_t)(cc)) * RF + 2 * lane;    \
    asm volatile("global_load_dwordx2 %0, %1, off" : "=v"(rg[SLOT][0]) : "v"(_s));          \
    asm volatile("global_load_dwordx2 %0, %1, off" : "=v"(rg[SLOT][1]) : "v"(_s + RF));     \
    asm volatile("global_load_dwordx2 %0, %1, off" : "=v"(rg[SLOT][2]) : "v"(_s + 2 * RF)); \
    asm volatile("global_load_dwordx2 %0, %1, off" : "=v"(rg[SLOT][3]) : "v"(_s + 3 * RF)); \
    asm volatile("global_load_dwordx2 %0, %1, off" : "=v"(rg[SLOT][4]) : "v"(_s + 4 * RF)); \
    asm volatile("global_load_dwordx2 %0, %1, off" : "=v"(rg[SLOT][5]) : "v"(_s + 5 * RF)); \
  } while (0)

// steady state: chunks c..c+7 in flight = 48 loads; wait to 42 -> chunk c done.
// Tying the slot's regs as "+v" makes every use of them depend on this wait.
#define WAITC(SLOT)                                                                  \
    asm volatile("s_waitcnt vmcnt(42)"                                               \
                 : "+v"(rg[SLOT][0]), "+v"(rg[SLOT][1]), "+v"(rg[SLOT][2]),          \
                   "+v"(rg[SLOT][3]), "+v"(rg[SLOT][4]), "+v"(rg[SLOT][5]))

#define SECTION(SLOT)                                                                \
    {                                                                                \
        PF6(((SLOT) + 7) & 7, min(c + 7, NCm1));                                     \
        WAITC(SLOT);                                                                 \
        const int toff = 1 + 6 * c;                                                  \
        float pv[6];                                                                 \
        pv[0] = pb_lds[toff];     pv[1] = pb_lds[toff + 1];                          \
        pv[2] = pb_lds[toff + 2]; pv[3] = pb_lds[toff + 3];                          \
        pv[4] = pb_lds[toff + 4]; pv[5] = pb_lds[toff + 5];                          \
        run6(rg[SLOT], pv, a0, a1, a2, a3, aX, msk1, msk3, f);                       \
        renorm(a0, a1, a2, a3, aX, Sc, f);                                           \
        if (++c >= NC) break;                                                        \
    }

__global__ __launch_bounds__(64) void ctc_dp(
        const float* __restrict__ labels, const float* __restrict__ pbuf,
        const int* __restrict__ targets, const int* __restrict__ in_len,
        const int* __restrict__ tg_len, float* __restrict__ out) {
    __shared__ float pb_lds[2048];          // 8 KB blank-prob row
    const int b = blockIdx.x;
    const int lane = threadIdx.x;            // 0..63, owns cells 4i..4i+3
    const int Tb = in_len[b];
    const int Sb = tg_len[b];
    const float* lab_base = labels + (size_t)b * CT * RF;
    const float* pb_base  = pbuf + (size_t)b * CT;

    const int tg0 = targets[b * CS + 2 * lane];
    const int tg1 = targets[b * CS + 2 * lane + 1];
    const int tgm = dpp_wshr1_i(tg1);        // targets[2i-1] (lane0: 0)
    const float msk1 = (tg0 != tgm) ? 1.f : 0.f;
    const float msk3 = (tg1 != tg0) ? 1.f : 0.f;

    // stage pb row to LDS: 8 x 256-float strips (last overlapped, stays in-bounds)
#pragma unroll
    for (int k = 0; k < 8; ++k) {
        const int start = (k * 256 + 256 <= CT) ? k * 256 : CT - 256;
        ((float4*)(pb_lds + start))[lane] = ((const float4*)(pb_base + start))[lane];
    }

    // t=0 init: alpha[0]=p_blank, alpha[1]=p(label 0)
    float a0 = 0.f, a1 = 0.f, a2 = 0.f, a3 = 0.f, aX = 0.f;
    {
        const float pb0 = pb_base[0];
        const float pl0 = lab_base[0];
        if (lane == 0) { a0 = pb0; a1 = pl0; }
    }
    int Sc = 0;
    float f = 1.f;
    renorm(a0, a1, a2, a3, aX, Sc, f);

    __syncthreads();   // drain staging loads/writes BEFORE any asm ring load

    const int NC = (Tb - 1) / 6;             // full 6-step chunks from t=1
    const int NCm1 = NC - 1;
    if (NC >= 1) {
        float2 rg[8][6];                      // 96-VGPR register ring
        PF6(0, 0);
        PF6(1, min(1, NCm1));
        PF6(2, min(2, NCm1));
        PF6(3, min(3, NCm1));
        PF6(4, min(4, NCm1));
        PF6(5, min(5, NCm1));
        PF6(6, min(6, NCm1));
        int c = 0;
        while (true) {
            SECTION(0)
            SECTION(1)
            SECTION(2)
            SECTION(3)
            SECTION(4)
            SECTION(5)
            SECTION(6)
            SECTION(7)
        }
    }
    // tail: t = 1+6*NC .. Tb-1 (<=5 steps); compiler's vmcnt(0) here drains ring
    for (int t = 1 + 6 * NC; t < Tb; ++t) {
        const float2 lb = *(const float2*)(lab_base + (size_t)t * RF + 2 * lane);
        const float pb = pb_lds[t];
        const float u3 = dpp_wshr1(a3) * f;
        const float n0 = (a0 + u3) * pb;
        const float n1 = fmaf(msk1, u3, a1 + a0) * lb.x;
        const float n2 = (a2 + a1) * pb;
        const float n3 = fmaf(msk3, a1, a3 + a2) * lb.y;
        const float nX = (aX + a3) * pb;
        a0 = n0; a1 = n1; a2 = n2; a3 = n3; aX = nX;
    }

    // final: ll = log(alpha[2*Sb] + alpha[2*Sb-1]); per-lane scales -> LSE
    const int idx1 = 2 * Sb;
    const int idx2 = (idx1 - 1 > 0) ? (idx1 - 1) : 0;
    const int b4 = 4 * lane;
    float cres = 0.f;
    if (b4 + 0 == idx1 || b4 + 0 == idx2) cres += a0;
    if (b4 + 1 == idx1 || b4 + 1 == idx2) cres += a1;
    if (b4 + 2 == idx1 || b4 + 2 == idx2) cres += a2;
    if (b4 + 3 == idx1 || b4 + 3 == idx2) cres += a3;
    if (lane == 63 && (idx1 == 256 || idx2 == 256)) cres += aX;

    float l2 = (cres > 0.f) ? (log2f(cres) + (float)Sc) : -1e30f;
    float M = l2;
#pragma unroll
    for (int m = 1; m < 64; m <<= 1) M = fmaxf(M, __shfl_xor(M, m, 64));
    float e = (cres > 0.f) ? exp2f(l2 - M) : 0.f;
#pragma unroll
    for (int m = 1; m < 64; m <<= 1) e += __shfl_xor(e, m, 64);
    if (lane == 0) {
        const float ll = (M + log2f(e)) * LN2_F;
        atomicAdd(out, -ll);
    }
}

extern "C" void kernel_launch(void* const* d_in, const int* in_sizes, int n_in,
                              void* d_out, int out_size, void* d_ws, size_t ws_size,
                              hipStream_t stream) {
    (void)in_sizes; (void)n_in; (void)out_size; (void)ws_size;
    const float* lp      = (const float*)d_in[0];
    const int*   targets = (const int*)d_in[1];
    const int*   in_len  = (const int*)d_in[2];
    const int*   tg_len  = (const int*)d_in[3];
    float* out    = (float*)d_out;
    float* labels = (float*)d_ws;                               // 32.77 MB
    float* pbuf   = (float*)d_ws + (size_t)CB * CT * RF;        // +256 KB

    ctc_gather<<<dim3(CB * CT), dim3(256), 0, stream>>>(lp, targets, labels, pbuf, out);
    ctc_dp<<<dim3(CB), dim3(64), 0, stream>>>(labels, pbuf, targets, in_len, tg_len, out);
}